// Round 1
// baseline (1058.170 us; speedup 1.0000x reference)
//
#include <hip/hip_runtime.h>

// ---------------------------------------------------------------------------
// GAE_IR_79499844649397: graph SAGE encoder + pair/img/compo MLPs, bf16 MFMA.
// Shapes: N_NODES=360(pad 384), FEAT=512, HID=2048, NODE_DIM=512, EMB=800,
// E=1262, B=256, K=114 -> neg rows 29184; batched rows M=29440=230*128.
// ---------------------------------------------------------------------------

typedef unsigned short u16;
typedef __bf16 bf16x8 __attribute__((ext_vector_type(8)));
typedef float f32x4 __attribute__((ext_vector_type(4)));

__device__ inline u16 f2bf_u(float f) {
  union { float f; unsigned u; } a; a.f = f;
  unsigned u = a.u + 0x7fffu + ((a.u >> 16) & 1u);   // RNE
  return (u16)(u >> 16);
}
__device__ inline float bf2f_u(u16 h) {
  union { unsigned u; float f; } a; a.u = ((unsigned)h) << 16; return a.f;
}

#define GLOAD16(gptr, lptr)                                                   \
  __builtin_amdgcn_global_load_lds(                                           \
      (__attribute__((address_space(1))) void*)(gptr),                        \
      (__attribute__((address_space(3))) void*)(lptr), 16, 0, 0)

// ---------------------------------------------------------------------------
// GEMM: C[M,N] = act(A[M,K] @ Bt[N,K]^T + bias). A,Bt bf16 row-major.
// M = gridDim.y*128 (exact), Bt padded to gridDim.x*128 rows (zeros).
// 128x128 tile, BK=32, 4 waves (2x2), each wave 4x4 frags of 16x16x32.
// ATOMF: split-K partial, atomicAdd f32 into Cf0 (no bias/act).
// REMAP: f32 rows <256 -> Cf0, rows>=256 -> Cf1 (theta/neg split).
// RSQ: atomicAdd per-row sum of squares (pre-norm) into rowsq.
// ---------------------------------------------------------------------------
template <int RELU, int OBF16, int RSQ, int REMAP, int ATOMF>
__global__ __launch_bounds__(256) void gemm_k(
    const u16* __restrict__ A, int lda,
    const u16* __restrict__ Bt, int ldb,
    const float* __restrict__ bias, int biasN,
    int N, int K, int ktChunk,
    u16* __restrict__ Cb, float* __restrict__ Cf0, float* __restrict__ Cf1,
    int ldc, float* __restrict__ rowsq) {
  __shared__ u16 As[128 * 32];
  __shared__ u16 Bs[128 * 32];
  const int tid = threadIdx.x;
  const int wave = tid >> 6, lane = tid & 63;
  const int lr = lane & 15, lg = lane >> 4;
  const int wr = wave >> 1, wc = wave & 1;
  const int m0 = blockIdx.y << 7, n0 = blockIdx.x << 7;

  f32x4 acc[4][4] = {};

  const size_t aOff = (size_t)(m0 + (tid >> 2)) * lda + ((tid & 3) << 3);
  const size_t bOff = (size_t)(n0 + (tid >> 2)) * ldb + ((tid & 3) << 3);
  const size_t aOff1 = aOff + (size_t)64 * lda;
  const size_t bOff1 = bOff + (size_t)64 * ldb;
  u16* AsW0 = As + (wave << 9);
  u16* AsW1 = As + 2048 + (wave << 9);
  u16* BsW0 = Bs + (wave << 9);
  u16* BsW1 = Bs + 2048 + (wave << 9);

  const int nK = K >> 5;
  const int kt0 = blockIdx.z * ktChunk;
  int ktEnd = kt0 + ktChunk; if (ktEnd > nK) ktEnd = nK;

  for (int kt = kt0; kt < ktEnd; ++kt) {
    const int k0 = kt << 5;
    GLOAD16(A + aOff + k0, AsW0);
    GLOAD16(A + aOff1 + k0, AsW1);
    GLOAD16(Bt + bOff + k0, BsW0);
    GLOAD16(Bt + bOff1 + k0, BsW1);
    __syncthreads();
    bf16x8 af[4], bv[4];
#pragma unroll
    for (int m = 0; m < 4; ++m)
      af[m] = *(const bf16x8*)(As + ((((wr << 6) + (m << 4) + lr)) << 5) + (lg << 3));
#pragma unroll
    for (int n = 0; n < 4; ++n)
      bv[n] = *(const bf16x8*)(Bs + ((((wc << 6) + (n << 4) + lr)) << 5) + (lg << 3));
#pragma unroll
    for (int m = 0; m < 4; ++m)
#pragma unroll
      for (int n = 0; n < 4; ++n)
        acc[m][n] = __builtin_amdgcn_mfma_f32_16x16x32_bf16(af[m], bv[n], acc[m][n], 0, 0, 0);
    __syncthreads();
  }

  const int gcb = n0 + (wc << 6);
  const int grb = m0 + (wr << 6) + (lg << 2);
#pragma unroll
  for (int m = 0; m < 4; ++m) {
#pragma unroll
    for (int r = 0; r < 4; ++r) {
      const int grow = grb + (m << 4) + r;
      float ss = 0.f;
#pragma unroll
      for (int n = 0; n < 4; ++n) {
        const int gc = gcb + (n << 4) + lr;
        float v = acc[m][n][r];
        if (!ATOMF) {
          if (gc < biasN) v += bias[gc];
          if (RELU) v = fmaxf(v, 0.f);
        }
        if (gc < N) {
          if (ATOMF) {
            atomicAdd(Cf0 + (size_t)grow * ldc + gc, v);
          } else if (OBF16) {
            Cb[(size_t)grow * ldc + gc] = f2bf_u(v);
          } else {
            float* op = (REMAP && grow >= 256) ? (Cf1 + (size_t)(grow - 256) * ldc)
                                               : (Cf0 + (size_t)grow * ldc);
            op[gc] = v;
          }
          if (RSQ) ss += v * v;
        }
      }
      if (RSQ) {
        ss += __shfl_xor(ss, 1); ss += __shfl_xor(ss, 2);
        ss += __shfl_xor(ss, 4); ss += __shfl_xor(ss, 8);
        if (lr == 0) atomicAdd(&rowsq[grow], ss);
      }
    }
  }
}

// --------------------------- weight packing --------------------------------
// dst[n][kOff+k] = bf16(src[k][n]); zeros outside (Ksrc,Nsrc). 16x16 LDS tile.
__global__ void k_pack(const float* __restrict__ src, int Ksrc, int Nsrc,
                       u16* __restrict__ dst, int dstLd, int kOff) {
  __shared__ float t[16][17];
  const int k0 = blockIdx.x * 16, n0 = blockIdx.y * 16;
  const int tx = threadIdx.x, ty = threadIdx.y;
  const int km = k0 + ty, n = n0 + tx;
  float v = (km < Ksrc && n < Nsrc) ? src[(size_t)km * Nsrc + n] : 0.f;
  t[ty][tx] = v;
  __syncthreads();
  dst[(size_t)(n0 + ty) * dstLd + kOff + k0 + tx] = f2bf_u(t[tx][ty]);
}

// Split-bf16 stacked pack: logical W[Ktot][Nsrc] = [srcA(splitK rows); srcB].
// dst[n][k], k in [0,3*Ktot): blocks [Whi, Whi, Wlo].
__global__ void k_pack_split(const float* __restrict__ srcA, const float* __restrict__ srcB,
                             int splitK, int Ktot, int Nsrc,
                             u16* __restrict__ dst, int dstLd) {
  __shared__ float t[16][17];
  const int k0 = blockIdx.x * 16, n0 = blockIdx.y * 16;
  const int tx = threadIdx.x, ty = threadIdx.y;
  int kOut = k0 + ty;
  int blk = kOut / Ktot; int km = kOut - blk * Ktot;
  const int n = n0 + tx;
  float v = 0.f;
  if (n < Nsrc)
    v = (km < splitK) ? srcA[(size_t)km * Nsrc + n]
                      : srcB[(size_t)(km - splitK) * Nsrc + n];
  t[ty][tx] = v;
  __syncthreads();
  const int kw = k0 + tx;
  const int blkw = kw / Ktot;
  float x = t[tx][ty];
  u16 hb = f2bf_u(x);
  u16 o = (blkw == 2) ? f2bf_u(x - bf2f_u(hb)) : hb;
  dst[(size_t)(n0 + ty) * dstLd + kw] = o;
}

// --------------------------- graph aggregation -----------------------------
__global__ void k_cnt(const int* __restrict__ ed, float* __restrict__ cntf, int E) {
  int i = blockIdx.x * 256 + threadIdx.x;
  if (i < E) atomicAdd(&cntf[ed[i]], 1.f);
}
__global__ void k_agg(const int* __restrict__ es, const int* __restrict__ ed,
                      const float* __restrict__ x, float* __restrict__ agg, int E, int D) {
  int idx = blockIdx.x * 256 + threadIdx.x;
  if (idx >= E * D) return;
  int e = idx / D, d = idx - e * D;
  atomicAdd(&agg[(size_t)ed[e] * D + d], x[(size_t)es[e] * D + d]);
}

// A'g [384][3072] = blocks [hi, lo, hi] of [agg0/cnt | nodes]
__global__ void k_build_agp(const float* __restrict__ nodes, const float* __restrict__ agg0f,
                            const float* __restrict__ cntf, u16* __restrict__ Agp) {
  int idx = blockIdx.x * 256 + threadIdx.x;
  if (idx >= 384 * 3072) return;
  int r = idx / 3072, c = idx - r * 3072;
  u16 o = 0;
  if (r < 360) {
    int blk = c >> 10, km = c & 1023;
    float x = (km < 512) ? agg0f[r * 512 + km] / fmaxf(cntf[r], 1.f)
                         : nodes[r * 512 + km - 512];
    u16 hb = f2bf_u(x);
    o = (blk == 1) ? f2bf_u(x - bf2f_u(hb)) : hb;
  }
  Agp[idx] = o;
}

// A2' [384][12288] = blocks [hi, lo, hi] of [agg1/cnt | h]
__global__ void k_build_a2p(const float* __restrict__ Hf, const float* __restrict__ agg1f,
                            const float* __restrict__ cntf, u16* __restrict__ A2p) {
  int idx = blockIdx.x * 256 + threadIdx.x;
  if (idx >= 384 * 12288) return;
  int r = idx / 12288, c = idx - r * 12288;
  u16 o = 0;
  if (r < 360) {
    int blk = c / 4096, km = c - blk * 4096;
    float x = (km < 2048) ? agg1f[r * 2048 + km] / fmaxf(cntf[r], 1.f)
                          : Hf[r * 2048 + km - 2048];
    u16 hb = f2bf_u(x);
    o = (blk == 1) ? f2bf_u(x - bf2f_u(hb)) : hb;
  }
  A2p[idx] = o;
}

__global__ void k_relu_bias_f32(const float* __restrict__ acc, const float* __restrict__ bias,
                                float* __restrict__ out, int N, int total) {
  int idx = blockIdx.x * 256 + threadIdx.x;
  if (idx >= total) return;
  out[idx] = fmaxf(acc[idx] + bias[idx % N], 0.f);
}
__global__ void k_bias_bf16(const float* __restrict__ acc, const float* __restrict__ bias,
                            u16* __restrict__ out, int N, int total) {
  int idx = blockIdx.x * 256 + threadIdx.x;
  if (idx >= total) return;
  out[idx] = f2bf_u(acc[idx] + bias[idx % N]);
}

// P [29440][1024]: row<256 -> [z[t_attr[r]] | z[115+obj[r]]];
// row>=256: rr=r-256, b=rr/114 -> [z[neg_attr[rr]] | z[115+obj[b]]]. 16B copies.
__global__ void k_buildP(const u16* __restrict__ Zb, const int* __restrict__ t_attr,
                         const int* __restrict__ obj, const int* __restrict__ negat,
                         u16* __restrict__ P) {
  int idx = blockIdx.x * 256 + threadIdx.x;      // 29440*128 chunks of 8 elems
  if (idx >= 29440 * 128) return;
  int r = idx >> 7, ch = idx & 127, c = ch << 3;
  int attr, b;
  if (r < 256) { attr = t_attr[r]; b = r; }
  else { int rr = r - 256; attr = negat[rr]; b = rr / 114; }
  int node = (c < 512) ? attr : (115 + obj[b]);
  int cc = (c < 512) ? c : c - 512;
  *(uint4*)(P + ((size_t)r << 10) + c) = *(const uint4*)(Zb + node * 512 + cc);
}

// X [29440][1312]: cols 0..511 = bf16(s_img[b]); 4 floats/thread.
__global__ void k_fill_simg(const float* __restrict__ s_img, u16* __restrict__ X) {
  int idx = blockIdx.x * 256 + threadIdx.x;      // 29440*128 chunks of 4
  if (idx >= 29440 * 128) return;
  int r = idx >> 7, ch = idx & 127, c = ch << 2;
  int b = (r < 256) ? r : (r - 256) / 114;
  float4 v = *(const float4*)(s_img + b * 512 + c);
  ushort4 o;
  o.x = f2bf_u(v.x); o.y = f2bf_u(v.y); o.z = f2bf_u(v.z); o.w = f2bf_u(v.w);
  *(ushort4*)(X + (size_t)r * 1312 + c) = o;
}

__global__ void k_cvt_bf16(const float* __restrict__ src, u16* __restrict__ dst, int n4) {
  int idx = blockIdx.x * 256 + threadIdx.x;
  if (idx >= n4) return;
  float4 v = *(const float4*)(src + (idx << 2));
  ushort4 o;
  o.x = f2bf_u(v.x); o.y = f2bf_u(v.y); o.z = f2bf_u(v.z); o.w = f2bf_u(v.w);
  *(ushort4*)(dst + ((size_t)idx << 2)) = o;
}

// In-place L2 norm of bf16 rows (800 cols, ld 1312) given precomputed sumsq.
__global__ void k_norm_bf16(u16* __restrict__ Xp, const float* __restrict__ rowsq) {
  int r = blockIdx.x;
  float s = 1.f / sqrtf(fmaxf(rowsq[r], 1e-24f));
  u16* row = Xp + (size_t)r * 1312;
  int c = threadIdx.x;
  if (c < 200) {
    ushort4 v = *(ushort4*)(row + (c << 2));
    v.x = f2bf_u(bf2f_u(v.x) * s); v.y = f2bf_u(bf2f_u(v.y) * s);
    v.z = f2bf_u(bf2f_u(v.z) * s); v.w = f2bf_u(bf2f_u(v.w) * s);
    *(ushort4*)(row + (c << 2)) = v;
  }
}

// In-place L2 norm of f32 rows (800 cols, ld 800); rows<split at o0 else o1.
__global__ void k_norm_f32(float* __restrict__ o0, float* __restrict__ o1,
                           const float* __restrict__ rowsq, int split) {
  int r = blockIdx.x;
  float s = 1.f / sqrtf(fmaxf(rowsq[r], 1e-24f));
  float* row = (r < split) ? (o0 + (size_t)r * 800) : (o1 + (size_t)(r - split) * 800);
  int c = threadIdx.x;
  if (c < 200) {
    float4 v = *(float4*)(row + (c << 2));
    v.x *= s; v.y *= s; v.z *= s; v.w *= s;
    *(float4*)(row + (c << 2)) = v;
  }
}

// ---------------------------------------------------------------------------
extern "C" void kernel_launch(void* const* d_in, const int* in_sizes, int n_in,
                              void* d_out, int out_size, void* d_ws, size_t ws_size,
                              hipStream_t stream) {
  const float* nodes = (const float*)d_in[0];
  const float* s_img = (const float*)d_in[1];
  const float* t_img = (const float*)d_in[2];
  const float* Wl1 = (const float*)d_in[3];
  const float* Wr1 = (const float*)d_in[4];
  const float* b1  = (const float*)d_in[5];
  const float* Wl2 = (const float*)d_in[6];
  const float* Wr2 = (const float*)d_in[7];
  const float* b2  = (const float*)d_in[8];
  const float* Wp1 = (const float*)d_in[9];
  const float* bp1 = (const float*)d_in[10];
  const float* Wp2 = (const float*)d_in[11];
  const float* bp2 = (const float*)d_in[12];
  const float* Wi1 = (const float*)d_in[13];
  const float* bi1 = (const float*)d_in[14];
  const float* Wi2 = (const float*)d_in[15];
  const float* bi2 = (const float*)d_in[16];
  const float* Wi3 = (const float*)d_in[17];
  const float* bi3 = (const float*)d_in[18];
  const float* Wc1 = (const float*)d_in[19];
  const float* bc1 = (const float*)d_in[20];
  const float* Wc2 = (const float*)d_in[21];
  const float* bc2 = (const float*)d_in[22];
  const float* Wc3 = (const float*)d_in[23];
  const float* bc3 = (const float*)d_in[24];
  const int* e_src = (const int*)d_in[25];
  const int* e_dst = (const int*)d_in[26];
  const int* t_attr = (const int*)d_in[27];
  const int* obj    = (const int*)d_in[28];
  const int* negat  = (const int*)d_in[29];
  (void)in_sizes; (void)n_in; (void)out_size; (void)ws_size;

  float* out = (float*)d_out;             // theta[256*800] | targets[256*800] | neg[29184*800]

  char* p = (char*)d_ws;
  auto alloc = [&](size_t bytes) -> void* {
    char* r = p; p += (bytes + 255) & ~(size_t)255; return (void*)r;
  };
  // packed transposed weights [Np128][K] bf16
  u16* W1t  = (u16*)alloc(2048ull * 3072 * 2);   // split [Wl1;Wr1] K'=3*1024
  u16* W2t  = (u16*)alloc(512ull * 12288 * 2);   // split [Wl2;Wr2] K'=3*4096
  u16* Wp1t = (u16*)alloc(1024ull * 1024 * 2);
  u16* Wp2t = (u16*)alloc(896ull * 1024 * 2);
  u16* Wc1t = (u16*)alloc(896ull * 1312 * 2);
  u16* Wc2t = (u16*)alloc(1024ull * 800 * 2);
  u16* Wc3t = (u16*)alloc(896ull * 1024 * 2);
  u16* Wi1t = (u16*)alloc(896ull * 512 * 2);
  u16* Wi2t = (u16*)alloc(1024ull * 800 * 2);
  u16* Wi3t = (u16*)alloc(896ull * 1024 * 2);
  // SAGE activations
  u16*  Agp  = (u16*)alloc(384ull * 3072 * 2);
  float* Hacc = (float*)alloc(384ull * 2048 * 4);
  float* Hf   = (float*)alloc(384ull * 2048 * 4);
  u16*  A2p  = (u16*)alloc(384ull * 12288 * 2);
  float* Zacc = (float*)alloc(384ull * 512 * 4);
  u16*  Zb   = (u16*)alloc(384ull * 512 * 2);
  u16*  Timg = (u16*)alloc(256ull * 512 * 2);
  u16*  T1   = (u16*)alloc(256ull * 800 * 2);
  u16*  T2   = (u16*)alloc(256ull * 1024 * 2);
  float* agg0f = (float*)alloc(384ull * 512 * 4);
  float* agg1f = (float*)alloc(384ull * 2048 * 4);
  float* cntf  = (float*)alloc(384 * 4);
  float* rowsqP = (float*)alloc(29440ull * 4);
  float* rowsqC = (float*)alloc(29440ull * 4);
  float* rowsqT = (float*)alloc(256 * 4);
  // big activations (H2 aliases P, H3 aliases H1 after they're dead)
  u16* P  = (u16*)alloc(29440ull * 1024 * 2);
  u16* H1 = (u16*)alloc(29440ull * 1024 * 2);
  u16* X  = (u16*)alloc(29440ull * 1312 * 2);
  u16* H2 = P;
  u16* H3 = H1;

  // zero atomically-accumulated scratch (required every call; ws not re-poisoned)
  hipMemsetAsync(Hacc, 0, 384ull * 2048 * 4, stream);
  hipMemsetAsync(Zacc, 0, 384ull * 512 * 4, stream);
  hipMemsetAsync(agg0f, 0, 384ull * 512 * 4, stream);
  hipMemsetAsync(agg1f, 0, 384ull * 2048 * 4, stream);
  hipMemsetAsync(cntf, 0, 384 * 4, stream);
  hipMemsetAsync(rowsqP, 0, 29440ull * 4, stream);
  hipMemsetAsync(rowsqC, 0, 29440ull * 4, stream);
  hipMemsetAsync(rowsqT, 0, 256 * 4, stream);

  dim3 tb(16, 16);
  // weight packs (transpose + bf16 + pad)
  k_pack_split<<<dim3(3072 / 16, 2048 / 16), tb, 0, stream>>>(Wl1, Wr1, 512, 1024, 2048, W1t, 3072);
  k_pack_split<<<dim3(12288 / 16, 512 / 16), tb, 0, stream>>>(Wl2, Wr2, 2048, 4096, 512, W2t, 12288);
  k_pack<<<dim3(1024 / 16, 1024 / 16), tb, 0, stream>>>(Wp1, 1024, 1000, Wp1t, 1024, 0);
  k_pack<<<dim3(1024 / 16, 896 / 16),  tb, 0, stream>>>(Wp2, 1000, 800,  Wp2t, 1024, 0);
  k_pack<<<dim3(1312 / 16, 896 / 16),  tb, 0, stream>>>(Wc1, 1312, 800,  Wc1t, 1312, 0);
  k_pack<<<dim3(800 / 16, 1024 / 16),  tb, 0, stream>>>(Wc2, 800, 1000,  Wc2t, 800, 0);
  k_pack<<<dim3(1024 / 16, 896 / 16),  tb, 0, stream>>>(Wc3, 1000, 800,  Wc3t, 1024, 0);
  k_pack<<<dim3(512 / 16, 896 / 16),   tb, 0, stream>>>(Wi1, 512, 800,   Wi1t, 512, 0);
  k_pack<<<dim3(800 / 16, 1024 / 16),  tb, 0, stream>>>(Wi2, 800, 1000,  Wi2t, 800, 0);
  k_pack<<<dim3(1024 / 16, 896 / 16),  tb, 0, stream>>>(Wi3, 1000, 800,  Wi3t, 1024, 0);

  // SAGE layer 1
  k_cnt<<<dim3((1262 + 255) / 256), 256, 0, stream>>>(e_dst, cntf, 1262);
  k_agg<<<dim3((1262 * 512 + 255) / 256), 256, 0, stream>>>(e_src, e_dst, nodes, agg0f, 1262, 512);
  k_build_agp<<<dim3((384 * 3072 + 255) / 256), 256, 0, stream>>>(nodes, agg0f, cntf, Agp);
  gemm_k<0, 0, 0, 0, 1><<<dim3(16, 3, 4), 256, 0, stream>>>(
      Agp, 3072, W1t, 3072, nullptr, 0, 2048, 3072, 24, nullptr, Hacc, nullptr, 2048, nullptr);
  k_relu_bias_f32<<<dim3((384 * 2048 + 255) / 256), 256, 0, stream>>>(Hacc, b1, Hf, 2048, 384 * 2048);
  // SAGE layer 2
  k_agg<<<dim3((1262 * 2048 + 255) / 256), 256, 0, stream>>>(e_src, e_dst, Hf, agg1f, 1262, 2048);
  k_build_a2p<<<dim3((384 * 12288 + 255) / 256), 256, 0, stream>>>(Hf, agg1f, cntf, A2p);
  gemm_k<0, 0, 0, 0, 1><<<dim3(4, 3, 8), 256, 0, stream>>>(
      A2p, 12288, W2t, 12288, nullptr, 0, 512, 12288, 48, nullptr, Zacc, nullptr, 512, nullptr);
  k_bias_bf16<<<dim3((384 * 512 + 255) / 256), 256, 0, stream>>>(Zacc, b2, Zb, 512, 384 * 512);

  // gathers / broadcasts
  k_buildP<<<dim3(29440 * 128 / 256), 256, 0, stream>>>(Zb, t_attr, obj, negat, P);
  k_fill_simg<<<dim3(29440 * 128 / 256), 256, 0, stream>>>(s_img, X);
  k_cvt_bf16<<<dim3((256 * 512 / 4 + 255) / 256), 256, 0, stream>>>(t_img, Timg, 256 * 512 / 4);

  // pair_fc over 29440 rows (t-branch rows 0..255 + neg rows)
  gemm_k<1, 1, 0, 0, 0><<<dim3(8, 230, 1), 256, 0, stream>>>(
      P, 1024, Wp1t, 1024, bp1, 1000, 1024, 1024, 1 << 20, H1, nullptr, nullptr, 1024, nullptr);
  gemm_k<0, 1, 1, 0, 0><<<dim3(7, 230, 1), 256, 0, stream>>>(
      H1, 1024, Wp2t, 1024, bp2, 800, 800, 1024, 1 << 20, X + 512, nullptr, nullptr, 1312, rowsqP);
  k_norm_bf16<<<dim3(29440), 256, 0, stream>>>(X + 512, rowsqP);

  // compo mlp3 over 29440 rows -> theta (rows<256) + neg (rows>=256)
  gemm_k<1, 1, 0, 0, 0><<<dim3(7, 230, 1), 256, 0, stream>>>(
      X, 1312, Wc1t, 1312, bc1, 800, 800, 1312, 1 << 20, H2, nullptr, nullptr, 800, nullptr);
  gemm_k<1, 1, 0, 0, 0><<<dim3(8, 230, 1), 256, 0, stream>>>(
      H2, 800, Wc2t, 800, bc2, 1000, 1024, 800, 1 << 20, H3, nullptr, nullptr, 1024, nullptr);
  gemm_k<0, 0, 1, 1, 0><<<dim3(7, 230, 1), 256, 0, stream>>>(
      H3, 1024, Wc3t, 1024, bc3, 800, 800, 1024, 1 << 20, nullptr, out, out + 409600, 800, rowsqC);
  k_norm_f32<<<dim3(29440), 256, 0, stream>>>(out, out + 409600, rowsqC, 256);

  // targets = img mlp3
  gemm_k<1, 1, 0, 0, 0><<<dim3(7, 2, 1), 256, 0, stream>>>(
      Timg, 512, Wi1t, 512, bi1, 800, 800, 512, 1 << 20, T1, nullptr, nullptr, 800, nullptr);
  gemm_k<1, 1, 0, 0, 0><<<dim3(8, 2, 1), 256, 0, stream>>>(
      T1, 800, Wi2t, 800, bi2, 1000, 1024, 800, 1 << 20, T2, nullptr, nullptr, 1024, nullptr);
  gemm_k<0, 0, 1, 0, 0><<<dim3(7, 2, 1), 256, 0, stream>>>(
      T2, 1024, Wi3t, 1024, bi3, 800, 800, 1024, 1 << 20, nullptr, out + 204800, nullptr, 800, rowsqT);
  k_norm_f32<<<dim3(256), 256, 0, stream>>>(out + 204800, nullptr, rowsqT, 1 << 30);
}

// Round 2
// 872.647 us; speedup vs baseline: 1.2126x; 1.2126x over previous
//
#include <hip/hip_runtime.h>

// ---------------------------------------------------------------------------
// GAE_IR_79499844649397: graph SAGE encoder + pair/img/compo MLPs, bf16 MFMA.
// M=29440 (=230*128) big rows + 256 fused img rows (2 panels per dispatch).
// 128x128 tile, BK=32, LDS double-buffer + counted vmcnt(4), XCD swizzle.
// ---------------------------------------------------------------------------

typedef unsigned short u16;
typedef __bf16 bf16x8 __attribute__((ext_vector_type(8)));
typedef float f32x4 __attribute__((ext_vector_type(4)));

__device__ inline u16 f2bf_u(float f) {
  union { float f; unsigned u; } a; a.f = f;
  unsigned u = a.u + 0x7fffu + ((a.u >> 16) & 1u);   // RNE
  return (u16)(u >> 16);
}
__device__ inline float bf2f_u(u16 h) {
  union { unsigned u; float f; } a; a.u = ((unsigned)h) << 16; return a.f;
}

#define GLOAD16(gptr, lptr)                                                   \
  __builtin_amdgcn_global_load_lds(                                           \
      (__attribute__((address_space(1))) void*)(gptr),                        \
      (__attribute__((address_space(3))) void*)(lptr), 16, 0, 0)

struct Panel {
  const u16* A; int lda;
  const u16* B; int ldb;
  const float* bias; int biasN;
  int N; int nK;
  void* out; int ldc;
};

// MODE 0: bf16 out + bias + relu
// MODE 1: bf16 out + bias, + rowsq (pre-norm sumsq)
// MODE 2: f32 atomicAdd split-K partial (no bias/act)
// MODE 3: f32 out + bias, 3-range remap (theta/neg/targets) + rowsq
template <int MODE>
__global__ __launch_bounds__(256) void gemm2(
    Panel p0, Panel p1, int yb, int ktChunk,
    float* __restrict__ rowsq,
    float* __restrict__ cTheta, float* __restrict__ cNeg, float* __restrict__ cTgt) {
  __shared__ u16 As[2][4096];
  __shared__ u16 Bs[2][4096];

  // chunked-bijective XCD swizzle: each XCD gets contiguous row-panels
  const int nwg = gridDim.x * gridDim.y;
  const int orig = blockIdx.y * gridDim.x + blockIdx.x;
  const int q = nwg >> 3, r = nwg & 7, xcd = orig & 7;
  const int basewg = (xcd < r) ? xcd * (q + 1) : r * (q + 1) + (xcd - r) * q;
  const int wg = basewg + (orig >> 3);
  const int bx = wg % gridDim.x, by = wg / gridDim.x;

  const Panel P = (by < yb) ? p0 : p1;
  const int rowOff = (by < yb) ? 0 : (yb << 7);
  const int m0g = by << 7;           // global row base
  const int m0 = m0g - rowOff;       // row base within this panel's A / out
  const int n0 = bx << 7;

  const int tid = threadIdx.x;
  const int wave = tid >> 6, lane = tid & 63;
  const int lr = lane & 15, lg = lane >> 4;
  const int wr = wave >> 1, wc = wave & 1;

  f32x4 acc[4][4] = {};

  const size_t aOff  = (size_t)(m0 + (tid >> 2)) * P.lda + ((tid & 3) << 3);
  const size_t aOff1 = aOff + (size_t)64 * P.lda;
  const size_t bOff  = (size_t)(n0 + (tid >> 2)) * P.ldb + ((tid & 3) << 3);
  const size_t bOff1 = bOff + (size_t)64 * P.ldb;

  const int nK = P.nK;
  const int kt0 = blockIdx.z * ktChunk;
  int ktEnd = kt0 + ktChunk; if (ktEnd > nK) ktEnd = nK;

  auto stage = [&](int kt, int b) {
    const int k0 = kt << 5;
    u16* Ad = &As[b][wave << 9];
    u16* Bd = &Bs[b][wave << 9];
    GLOAD16(P.A + aOff + k0, Ad);
    GLOAD16(P.A + aOff1 + k0, Ad + 2048);
    GLOAD16(P.B + bOff + k0, Bd);
    GLOAD16(P.B + bOff1 + k0, Bd + 2048);
  };

  if (kt0 < ktEnd) stage(kt0, 0);
  for (int kt = kt0; kt < ktEnd; ++kt) {
    const int cb = (kt - kt0) & 1;
    if (kt + 1 < ktEnd) {
      stage(kt + 1, cb ^ 1);                         // next tile in flight
      asm volatile("s_waitcnt vmcnt(4)" ::: "memory");  // only cur tile landed
    } else {
      asm volatile("s_waitcnt vmcnt(0)" ::: "memory");
    }
    __builtin_amdgcn_s_barrier();
    asm volatile("" ::: "memory");

    bf16x8 af[4], bv[4];
#pragma unroll
    for (int m = 0; m < 4; ++m)
      af[m] = *(const bf16x8*)(&As[cb][(((wr << 6) + (m << 4) + lr) << 5) + (lg << 3)]);
#pragma unroll
    for (int n = 0; n < 4; ++n)
      bv[n] = *(const bf16x8*)(&Bs[cb][(((wc << 6) + (n << 4) + lr) << 5) + (lg << 3)]);
#pragma unroll
    for (int m = 0; m < 4; ++m)
#pragma unroll
      for (int n = 0; n < 4; ++n)
        acc[m][n] = __builtin_amdgcn_mfma_f32_16x16x32_bf16(af[m], bv[n], acc[m][n], 0, 0, 0);

    asm volatile("s_waitcnt lgkmcnt(0)" ::: "memory");  // reads done before overwrite
    __builtin_amdgcn_s_barrier();
    asm volatile("" ::: "memory");
  }

  const int gcb = n0 + (wc << 6);
  const int grb = m0 + (wr << 6) + (lg << 2);    // panel-local row
  const int grbG = m0g + (wr << 6) + (lg << 2);  // global row
#pragma unroll
  for (int m = 0; m < 4; ++m) {
#pragma unroll
    for (int rr = 0; rr < 4; ++rr) {
      const int grow = grb + (m << 4) + rr;
      const int growG = grbG + (m << 4) + rr;
      float ss = 0.f;
#pragma unroll
      for (int n = 0; n < 4; ++n) {
        const int gc = gcb + (n << 4) + lr;
        if (gc >= P.N) continue;
        float v = acc[m][n][rr];
        if (MODE == 2) {
          atomicAdd((float*)P.out + (size_t)grow * P.ldc + gc, v);
        } else {
          if (gc < P.biasN) v += P.bias[gc];
          if (MODE == 0) {
            v = fmaxf(v, 0.f);
            ((u16*)P.out)[(size_t)grow * P.ldc + gc] = f2bf_u(v);
          } else if (MODE == 1) {
            ((u16*)P.out)[(size_t)grow * P.ldc + gc] = f2bf_u(v);
            ss += v * v;
          } else {  // MODE 3
            float* op = (growG < 256) ? cTheta + (size_t)growG * 800
                      : (growG < 29440) ? cNeg + (size_t)(growG - 256) * 800
                                        : cTgt + (size_t)(growG - 29440) * 800;
            op[gc] = v;
            ss += v * v;
          }
        }
      }
      if (MODE == 1 || MODE == 3) {
        ss += __shfl_xor(ss, 1); ss += __shfl_xor(ss, 2);
        ss += __shfl_xor(ss, 4); ss += __shfl_xor(ss, 8);
        if (lr == 0) atomicAdd(&rowsq[growG], ss);
      }
    }
  }
}

// --------------------------- weight packing --------------------------------
// dst[n][k] = bf16(src[k][n]) for k<Ksrc,n<Nsrc; zero elsewhere in grid range.
__global__ void k_pack(const float* __restrict__ src, int Ksrc, int Nsrc,
                       u16* __restrict__ dst, int dstLd) {
  __shared__ float t[16][17];
  const int k0 = blockIdx.x * 16, n0 = blockIdx.y * 16;
  const int tx = threadIdx.x, ty = threadIdx.y;
  const int km = k0 + ty, n = n0 + tx;
  float v = (km < Ksrc && n < Nsrc) ? src[(size_t)km * Nsrc + n] : 0.f;
  t[ty][tx] = v;
  __syncthreads();
  dst[(size_t)(n0 + ty) * dstLd + k0 + tx] = f2bf_u(t[tx][ty]);
}

// Split-bf16 stacked pack: logical W[Ktot][Nsrc] = [srcA(splitK rows); srcB].
// dst[n][k], k in [0,3*Ktot): blocks [Whi, Whi, Wlo].
__global__ void k_pack_split(const float* __restrict__ srcA, const float* __restrict__ srcB,
                             int splitK, int Ktot, int Nsrc,
                             u16* __restrict__ dst, int dstLd) {
  __shared__ float t[16][17];
  const int k0 = blockIdx.x * 16, n0 = blockIdx.y * 16;
  const int tx = threadIdx.x, ty = threadIdx.y;
  int kOut = k0 + ty;
  int blk = kOut / Ktot; int km = kOut - blk * Ktot;
  const int n = n0 + tx;
  float v = 0.f;
  if (n < Nsrc)
    v = (km < splitK) ? srcA[(size_t)km * Nsrc + n]
                      : srcB[(size_t)(km - splitK) * Nsrc + n];
  t[ty][tx] = v;
  __syncthreads();
  const int kw = k0 + tx;
  const int blkw = kw / Ktot;
  float x = t[tx][ty];
  u16 hb = f2bf_u(x);
  u16 o = (blkw == 2) ? f2bf_u(x - bf2f_u(hb)) : hb;
  dst[(size_t)(n0 + ty) * dstLd + kw] = o;
}

// --------------------------- graph aggregation -----------------------------
__global__ void k_cnt(const int* __restrict__ ed, float* __restrict__ cntf, int E) {
  int i = blockIdx.x * 256 + threadIdx.x;
  if (i < E) atomicAdd(&cntf[ed[i]], 1.f);
}
__global__ void k_agg(const int* __restrict__ es, const int* __restrict__ ed,
                      const float* __restrict__ x, float* __restrict__ agg, int E, int D) {
  int idx = blockIdx.x * 256 + threadIdx.x;
  if (idx >= E * D) return;
  int e = idx / D, d = idx - e * D;
  atomicAdd(&agg[(size_t)ed[e] * D + d], x[(size_t)es[e] * D + d]);
}

// A'g [384][3072] = blocks [hi, hi, lo] of [agg0/cnt | nodes]
__global__ void k_build_agp(const float* __restrict__ nodes, const float* __restrict__ agg0f,
                            const float* __restrict__ cntf, u16* __restrict__ Agp) {
  int idx = blockIdx.x * 256 + threadIdx.x;
  if (idx >= 384 * 3072) return;
  int r = idx / 3072, c = idx - r * 3072;
  u16 o = 0;
  if (r < 360) {
    int blk = c >> 10, km = c & 1023;
    float x = (km < 512) ? agg0f[r * 512 + km] / fmaxf(cntf[r], 1.f)
                         : nodes[r * 512 + km - 512];
    u16 hb = f2bf_u(x);
    o = (blk == 1) ? f2bf_u(x - bf2f_u(hb)) : hb;
  }
  Agp[idx] = o;
}

// A2' [384][12288] = blocks [hi, hi, lo] of [agg1/cnt | h]
__global__ void k_build_a2p(const float* __restrict__ Hf, const float* __restrict__ agg1f,
                            const float* __restrict__ cntf, u16* __restrict__ A2p) {
  int idx = blockIdx.x * 256 + threadIdx.x;
  if (idx >= 384 * 12288) return;
  int r = idx / 12288, c = idx - r * 12288;
  u16 o = 0;
  if (r < 360) {
    int blk = c / 4096, km = c - blk * 4096;
    float x = (km < 2048) ? agg1f[r * 2048 + km] / fmaxf(cntf[r], 1.f)
                          : Hf[r * 2048 + km - 2048];
    u16 hb = f2bf_u(x);
    o = (blk == 1) ? f2bf_u(x - bf2f_u(hb)) : hb;
  }
  A2p[idx] = o;
}

__global__ void k_relu_bias_f32(const float* __restrict__ acc, const float* __restrict__ bias,
                                float* __restrict__ out, int N, int total) {
  int idx = blockIdx.x * 256 + threadIdx.x;
  if (idx >= total) return;
  out[idx] = fmaxf(acc[idx] + bias[idx % N], 0.f);
}
__global__ void k_bias_bf16(const float* __restrict__ acc, const float* __restrict__ bias,
                            u16* __restrict__ out, int N, int total) {
  int idx = blockIdx.x * 256 + threadIdx.x;
  if (idx >= total) return;
  out[idx] = f2bf_u(acc[idx] + bias[idx % N]);
}

// P [29440][1024]: row<256 -> [z[t_attr[r]] | z[115+obj[r]]];
// row>=256: rr=r-256, b=rr/114 -> [z[neg_attr[rr]] | z[115+obj[b]]]. 16B copies.
__global__ void k_buildP(const u16* __restrict__ Zb, const int* __restrict__ t_attr,
                         const int* __restrict__ obj, const int* __restrict__ negat,
                         u16* __restrict__ P) {
  int idx = blockIdx.x * 256 + threadIdx.x;
  if (idx >= 29440 * 128) return;
  int r = idx >> 7, ch = idx & 127, c = ch << 3;
  int attr, b;
  if (r < 256) { attr = t_attr[r]; b = r; }
  else { int rr = r - 256; attr = negat[rr]; b = rr / 114; }
  int node = (c < 512) ? attr : (115 + obj[b]);
  int cc = (c < 512) ? c : c - 512;
  *(uint4*)(P + ((size_t)r << 10) + c) = *(const uint4*)(Zb + node * 512 + cc);
}

// X [29440][1312]: cols 0..511 = bf16(s_img[b]); 4 floats/thread.
__global__ void k_fill_simg(const float* __restrict__ s_img, u16* __restrict__ X) {
  int idx = blockIdx.x * 256 + threadIdx.x;
  if (idx >= 29440 * 128) return;
  int r = idx >> 7, ch = idx & 127, c = ch << 2;
  int b = (r < 256) ? r : (r - 256) / 114;
  float4 v = *(const float4*)(s_img + b * 512 + c);
  ushort4 o;
  o.x = f2bf_u(v.x); o.y = f2bf_u(v.y); o.z = f2bf_u(v.z); o.w = f2bf_u(v.w);
  *(ushort4*)(X + (size_t)r * 1312 + c) = o;
}

__global__ void k_cvt_bf16(const float* __restrict__ src, u16* __restrict__ dst, int n4) {
  int idx = blockIdx.x * 256 + threadIdx.x;
  if (idx >= n4) return;
  float4 v = *(const float4*)(src + (idx << 2));
  ushort4 o;
  o.x = f2bf_u(v.x); o.y = f2bf_u(v.y); o.z = f2bf_u(v.z); o.w = f2bf_u(v.w);
  *(ushort4*)(dst + ((size_t)idx << 2)) = o;
}

// In-place L2 norm of bf16 rows (800 cols, ld 1312) given precomputed sumsq.
__global__ void k_norm_bf16(u16* __restrict__ Xp, const float* __restrict__ rowsq) {
  int r = blockIdx.x;
  float s = 1.f / sqrtf(fmaxf(rowsq[r], 1e-24f));
  u16* row = Xp + (size_t)r * 1312;
  int c = threadIdx.x;
  if (c < 200) {
    ushort4 v = *(ushort4*)(row + (c << 2));
    v.x = f2bf_u(bf2f_u(v.x) * s); v.y = f2bf_u(bf2f_u(v.y) * s);
    v.z = f2bf_u(bf2f_u(v.z) * s); v.w = f2bf_u(bf2f_u(v.w) * s);
    *(ushort4*)(row + (c << 2)) = v;
  }
}

// L2 norm of all three f32 output regions (29696 rows total, 3-range remap).
__global__ void k_norm3(float* __restrict__ cTheta, float* __restrict__ cNeg,
                        float* __restrict__ cTgt, const float* __restrict__ rowsq) {
  int r = blockIdx.x;
  float s = 1.f / sqrtf(fmaxf(rowsq[r], 1e-24f));
  float* row = (r < 256) ? cTheta + (size_t)r * 800
             : (r < 29440) ? cNeg + (size_t)(r - 256) * 800
                           : cTgt + (size_t)(r - 29440) * 800;
  int c = threadIdx.x;
  if (c < 200) {
    float4 v = *(float4*)(row + (c << 2));
    v.x *= s; v.y *= s; v.z *= s; v.w *= s;
    *(float4*)(row + (c << 2)) = v;
  }
}

// ---------------------------------------------------------------------------
extern "C" void kernel_launch(void* const* d_in, const int* in_sizes, int n_in,
                              void* d_out, int out_size, void* d_ws, size_t ws_size,
                              hipStream_t stream) {
  const float* nodes = (const float*)d_in[0];
  const float* s_img = (const float*)d_in[1];
  const float* t_img = (const float*)d_in[2];
  const float* Wl1 = (const float*)d_in[3];
  const float* Wr1 = (const float*)d_in[4];
  const float* b1  = (const float*)d_in[5];
  const float* Wl2 = (const float*)d_in[6];
  const float* Wr2 = (const float*)d_in[7];
  const float* b2  = (const float*)d_in[8];
  const float* Wp1 = (const float*)d_in[9];
  const float* bp1 = (const float*)d_in[10];
  const float* Wp2 = (const float*)d_in[11];
  const float* bp2 = (const float*)d_in[12];
  const float* Wi1 = (const float*)d_in[13];
  const float* bi1 = (const float*)d_in[14];
  const float* Wi2 = (const float*)d_in[15];
  const float* bi2 = (const float*)d_in[16];
  const float* Wi3 = (const float*)d_in[17];
  const float* bi3 = (const float*)d_in[18];
  const float* Wc1 = (const float*)d_in[19];
  const float* bc1 = (const float*)d_in[20];
  const float* Wc2 = (const float*)d_in[21];
  const float* bc2 = (const float*)d_in[22];
  const float* Wc3 = (const float*)d_in[23];
  const float* bc3 = (const float*)d_in[24];
  const int* e_src = (const int*)d_in[25];
  const int* e_dst = (const int*)d_in[26];
  const int* t_attr = (const int*)d_in[27];
  const int* obj    = (const int*)d_in[28];
  const int* negat  = (const int*)d_in[29];
  (void)in_sizes; (void)n_in; (void)out_size; (void)ws_size;

  float* out = (float*)d_out;      // theta[256*800] | targets[256*800] | neg[29184*800]
  float* cTheta = out;
  float* cTgt = out + 204800;
  float* cNeg = out + 409600;

  char* p = (char*)d_ws;
  auto alloc = [&](size_t bytes) -> void* {
    char* r = p; p += (bytes + 255) & ~(size_t)255; return (void*)r;
  };
  // packed transposed weights [rows pad to x*128][K] bf16
  u16* W1t  = (u16*)alloc(2048ull * 3072 * 2);
  u16* W2t  = (u16*)alloc(512ull * 12288 * 2);
  u16* Wp1t = (u16*)alloc(1024ull * 1024 * 2);
  u16* Wp2t = (u16*)alloc(896ull * 1024 * 2);
  u16* Wc1t = (u16*)alloc(1024ull * 1312 * 2);
  u16* Wc2t = (u16*)alloc(1024ull * 896 * 2);
  u16* Wc3t = (u16*)alloc(896ull * 1024 * 2);
  u16* Wi1t = (u16*)alloc(1024ull * 512 * 2);
  u16* Wi2t = (u16*)alloc(1024ull * 800 * 2);
  u16* Wi3t = (u16*)alloc(896ull * 1024 * 2);
  // SAGE activations
  u16*  Agp  = (u16*)alloc(384ull * 3072 * 2);
  float* Hacc = (float*)alloc(384ull * 2048 * 4);
  float* Hf   = (float*)alloc(384ull * 2048 * 4);
  u16*  A2p  = (u16*)alloc(384ull * 12288 * 2);
  float* Zacc = (float*)alloc(384ull * 512 * 4);
  u16*  Zb   = (u16*)alloc(384ull * 512 * 2);
  u16*  Timg = (u16*)alloc(256ull * 512 * 2);
  u16*  T1   = (u16*)alloc(256ull * 800 * 2);
  u16*  T2   = (u16*)alloc(256ull * 1024 * 2);
  float* agg0f = (float*)alloc(384ull * 512 * 4);
  float* agg1f = (float*)alloc(384ull * 2048 * 4);
  float* cntf  = (float*)alloc(384 * 4);
  float* rowsqP = (float*)alloc(29440ull * 4);
  float* rowsqC = (float*)alloc(29696ull * 4);
  // big activations (H2 aliases P, H3 aliases H1 after they're dead)
  u16* P  = (u16*)alloc(29440ull * 1024 * 2);
  u16* H1 = (u16*)alloc(29440ull * 1024 * 2);
  u16* X  = (u16*)alloc(29440ull * 1312 * 2);
  u16* H2 = P;    // [29440][896]
  u16* H3 = H1;   // [29440][1024]

  hipMemsetAsync(Hacc, 0, 384ull * 2048 * 4, stream);
  hipMemsetAsync(Zacc, 0, 384ull * 512 * 4, stream);
  hipMemsetAsync(agg0f, 0, 384ull * 512 * 4, stream);
  hipMemsetAsync(agg1f, 0, 384ull * 2048 * 4, stream);
  hipMemsetAsync(cntf, 0, 384 * 4, stream);
  hipMemsetAsync(rowsqP, 0, 29440ull * 4, stream);
  hipMemsetAsync(rowsqC, 0, 29696ull * 4, stream);

  dim3 tb(16, 16);
  k_pack_split<<<dim3(192, 128), tb, 0, stream>>>(Wl1, Wr1, 512, 1024, 2048, W1t, 3072);
  k_pack_split<<<dim3(768, 32), tb, 0, stream>>>(Wl2, Wr2, 2048, 4096, 512, W2t, 12288);
  k_pack<<<dim3(64, 64), tb, 0, stream>>>(Wp1, 1024, 1000, Wp1t, 1024);
  k_pack<<<dim3(64, 56), tb, 0, stream>>>(Wp2, 1000, 800,  Wp2t, 1024);
  k_pack<<<dim3(82, 64), tb, 0, stream>>>(Wc1, 1312, 800,  Wc1t, 1312);
  k_pack<<<dim3(56, 64), tb, 0, stream>>>(Wc2, 800, 1000,  Wc2t, 896);
  k_pack<<<dim3(64, 56), tb, 0, stream>>>(Wc3, 1000, 800,  Wc3t, 1024);
  k_pack<<<dim3(32, 64), tb, 0, stream>>>(Wi1, 512, 800,   Wi1t, 512);
  k_pack<<<dim3(50, 64), tb, 0, stream>>>(Wi2, 800, 1000,  Wi2t, 800);
  k_pack<<<dim3(64, 56), tb, 0, stream>>>(Wi3, 1000, 800,  Wi3t, 1024);

  // SAGE layer 1
  k_cnt<<<dim3(5), 256, 0, stream>>>(e_dst, cntf, 1262);
  k_agg<<<dim3((1262 * 512 + 255) / 256), 256, 0, stream>>>(e_src, e_dst, nodes, agg0f, 1262, 512);
  k_build_agp<<<dim3(384 * 3072 / 256), 256, 0, stream>>>(nodes, agg0f, cntf, Agp);
  {
    Panel s0{Agp, 3072, W1t, 3072, nullptr, 0, 2048, 96, Hacc, 2048};
    gemm2<2><<<dim3(16, 3, 4), 256, 0, stream>>>(s0, s0, 1 << 20, 24, nullptr, nullptr, nullptr, nullptr);
  }
  k_relu_bias_f32<<<dim3(384 * 2048 / 256), 256, 0, stream>>>(Hacc, b1, Hf, 2048, 384 * 2048);
  // SAGE layer 2
  k_agg<<<dim3((1262 * 2048 + 255) / 256), 256, 0, stream>>>(e_src, e_dst, Hf, agg1f, 1262, 2048);
  k_build_a2p<<<dim3(384 * 12288 / 256), 256, 0, stream>>>(Hf, agg1f, cntf, A2p);
  {
    Panel s0{A2p, 12288, W2t, 12288, nullptr, 0, 512, 384, Zacc, 512};
    gemm2<2><<<dim3(4, 3, 8), 256, 0, stream>>>(s0, s0, 1 << 20, 48, nullptr, nullptr, nullptr, nullptr);
  }
  k_bias_bf16<<<dim3(384 * 512 / 256), 256, 0, stream>>>(Zacc, b2, Zb, 512, 384 * 512);

  // gathers / broadcasts
  k_buildP<<<dim3(29440 * 128 / 256), 256, 0, stream>>>(Zb, t_attr, obj, negat, P);
  k_fill_simg<<<dim3(29440 * 128 / 256), 256, 0, stream>>>(s_img, X);
  k_cvt_bf16<<<dim3(128), 256, 0, stream>>>(t_img, Timg, 256 * 512 / 4);

  // D1: pair_fc L1 (M=29440) + img L1 (M=256)
  {
    Panel s0{P, 1024, Wp1t, 1024, bp1, 1000, 1024, 32, H1, 1024};
    Panel s1{Timg, 512, Wi1t, 512, bi1, 800, 800, 16, T1, 800};
    gemm2<0><<<dim3(8, 232, 1), 256, 0, stream>>>(s0, s1, 230, 1 << 20, nullptr, nullptr, nullptr, nullptr);
  }
  // D2: pair_fc L2 (+rowsq) -> X[:,512:1312]
  {
    Panel s0{H1, 1024, Wp2t, 1024, bp2, 800, 800, 32, X + 512, 1312};
    gemm2<1><<<dim3(7, 230, 1), 256, 0, stream>>>(s0, s0, 1 << 20, 1 << 20, rowsqP, nullptr, nullptr, nullptr);
  }
  k_norm_bf16<<<dim3(29440), 256, 0, stream>>>(X + 512, rowsqP);

  // D3: compo L1 (M=29440) + img L2 (M=256)
  {
    Panel s0{X, 1312, Wc1t, 1312, bc1, 800, 896, 41, H2, 896};
    Panel s1{T1, 800, Wi2t, 800, bi2, 1000, 1024, 25, T2, 1024};
    gemm2<0><<<dim3(8, 232, 1), 256, 0, stream>>>(s0, s1, 230, 1 << 20, nullptr, nullptr, nullptr, nullptr);
  }
  // D4: compo L2
  {
    Panel s0{H2, 896, Wc2t, 896, bc2, 1000, 1024, 28, H3, 1024};
    gemm2<0><<<dim3(8, 230, 1), 256, 0, stream>>>(s0, s0, 1 << 20, 1 << 20, nullptr, nullptr, nullptr, nullptr);
  }
  // D5: compo L3 (theta+neg) + img L3 (targets), f32 out + rowsq
  {
    Panel s0{H3, 1024, Wc3t, 1024, bc3, 800, 800, 32, nullptr, 800};
    Panel s1{T2, 1024, Wi3t, 1024, bi3, 800, 800, 32, nullptr, 800};
    gemm2<3><<<dim3(7, 232, 1), 256, 0, stream>>>(s0, s1, 230, 1 << 20, rowsqC, cTheta, cNeg, cTgt);
  }
  k_norm3<<<dim3(29696), 256, 0, stream>>>(cTheta, cNeg, cTgt, rowsqC);
}